// Round 3
// baseline (1740.747 us; speedup 1.0000x reference)
//
#include <hip/hip_runtime.h>
#include <math.h>

namespace {

constexpr int kNCam  = 6;
constexpr int kInCh  = 256;
constexpr int kOutC  = 80;
constexpr int kDB    = 118;   // depth bins
constexpr int kFH    = 32;
constexpr int kFW    = 88;
constexpr int kHW    = kFH * kFW;       // 2816
constexpr int kNPix  = kNCam * kHW;     // 16896
constexpr int kFeatC = kDB + kOutC;     // 198
constexpr int kNX    = 360;
constexpr int kNVox  = kNX * kNX;       // 129600

// ---------------- 4x4 matrix inverses (fp64 cofactor) ----------------
// Geometry decision path is kept ENTIRELY in fp64 (inverse -> einsum ->
// binning) to match an fp64 numpy reference bit-near-exactly; any fp64
// inverse is accurate to ~1e-13 which is ~1e-11 of a voxel.
__global__ void prep_inverses_kernel(const float* __restrict__ aug,
                                     const float* __restrict__ l2i,
                                     double* __restrict__ invm) {
  const int t = threadIdx.x;
  if (t >= 12) return;
  const float* s = (t < 6) ? (aug + t * 16) : (l2i + (t - 6) * 16);
  double m[16];
#pragma unroll
  for (int i = 0; i < 16; ++i) m[i] = (double)s[i];
  double inv[16];
  inv[0]  =  m[5]*m[10]*m[15] - m[5]*m[11]*m[14] - m[9]*m[6]*m[15] + m[9]*m[7]*m[14] + m[13]*m[6]*m[11] - m[13]*m[7]*m[10];
  inv[4]  = -m[4]*m[10]*m[15] + m[4]*m[11]*m[14] + m[8]*m[6]*m[15] - m[8]*m[7]*m[14] - m[12]*m[6]*m[11] + m[12]*m[7]*m[10];
  inv[8]  =  m[4]*m[9]*m[15]  - m[4]*m[11]*m[13] - m[8]*m[5]*m[15] + m[8]*m[7]*m[13] + m[12]*m[5]*m[11] - m[12]*m[7]*m[9];
  inv[12] = -m[4]*m[9]*m[14]  + m[4]*m[10]*m[13] + m[8]*m[5]*m[14] - m[8]*m[6]*m[13] - m[12]*m[5]*m[10] + m[12]*m[6]*m[9];
  inv[1]  = -m[1]*m[10]*m[15] + m[1]*m[11]*m[14] + m[9]*m[2]*m[15] - m[9]*m[3]*m[14] - m[13]*m[2]*m[11] + m[13]*m[3]*m[10];
  inv[5]  =  m[0]*m[10]*m[15] - m[0]*m[11]*m[14] - m[8]*m[2]*m[15] + m[8]*m[3]*m[14] + m[12]*m[2]*m[11] - m[12]*m[3]*m[10];
  inv[9]  = -m[0]*m[9]*m[15]  + m[0]*m[11]*m[13] + m[8]*m[1]*m[15] - m[8]*m[3]*m[13] - m[12]*m[1]*m[11] + m[12]*m[3]*m[9];
  inv[13] =  m[0]*m[9]*m[14]  - m[0]*m[10]*m[13] - m[8]*m[1]*m[14] + m[8]*m[2]*m[13] + m[12]*m[1]*m[10] - m[12]*m[2]*m[9];
  inv[2]  =  m[1]*m[6]*m[15]  - m[1]*m[7]*m[14]  - m[5]*m[2]*m[15] + m[5]*m[3]*m[14] + m[13]*m[2]*m[7]  - m[13]*m[3]*m[6];
  inv[6]  = -m[0]*m[6]*m[15]  + m[0]*m[7]*m[14]  + m[4]*m[2]*m[15] - m[4]*m[3]*m[14] - m[12]*m[2]*m[7]  + m[12]*m[3]*m[6];
  inv[10] =  m[0]*m[5]*m[15]  - m[0]*m[7]*m[13]  - m[4]*m[1]*m[15] + m[4]*m[3]*m[13] + m[12]*m[1]*m[7]  - m[12]*m[3]*m[5];
  inv[14] = -m[0]*m[5]*m[14]  + m[0]*m[6]*m[13]  + m[4]*m[1]*m[14] - m[4]*m[2]*m[13] - m[12]*m[1]*m[6]  + m[12]*m[2]*m[5];
  inv[3]  = -m[1]*m[6]*m[11]  + m[1]*m[7]*m[10]  + m[5]*m[2]*m[11] - m[5]*m[3]*m[10] - m[9]*m[2]*m[7]   + m[9]*m[3]*m[6];
  inv[7]  =  m[0]*m[6]*m[11]  - m[0]*m[7]*m[10]  - m[4]*m[2]*m[11] + m[4]*m[3]*m[10] + m[8]*m[2]*m[7]   - m[8]*m[3]*m[6];
  inv[11] = -m[0]*m[5]*m[11]  + m[0]*m[7]*m[9]   + m[4]*m[1]*m[11] - m[4]*m[3]*m[9]  - m[8]*m[1]*m[7]   + m[8]*m[3]*m[5];
  inv[15] =  m[0]*m[5]*m[10]  - m[0]*m[6]*m[9]   - m[4]*m[1]*m[10] + m[4]*m[2]*m[9]  + m[8]*m[1]*m[6]   - m[8]*m[2]*m[5];
  const double det = m[0]*inv[0] + m[1]*inv[4] + m[2]*inv[8] + m[3]*inv[12];
  const double id = 1.0 / det;
#pragma unroll
  for (int i = 0; i < 16; ++i) invm[(size_t)t * 16 + i] = inv[i] * id;
}

// ---------------- depthnet 1x1 conv: feat[n][o][hw] ----------------
__global__ __launch_bounds__(256) void depthnet_gemm_kernel(
    const float* __restrict__ img, const float* __restrict__ wt,
    const float* __restrict__ bias, float* __restrict__ feat) {
  __shared__ float xs[16][256];
  const int tid = threadIdx.x;
  const int p0 = blockIdx.x * 256;       // 2816 % 256 == 0: never straddles cams
  const int n = p0 / kHW;
  const int hw0 = p0 - n * kHW;
  const int oc0 = blockIdx.y * 8;
  float acc[8] = {0.f, 0.f, 0.f, 0.f, 0.f, 0.f, 0.f, 0.f};
  const float* xb = img + (size_t)n * kInCh * kHW + hw0;
  for (int ic0 = 0; ic0 < kInCh; ic0 += 16) {
#pragma unroll
    for (int r = 0; r < 16; ++r)
      xs[r][tid] = xb[(size_t)(ic0 + r) * kHW + tid];
    __syncthreads();
#pragma unroll
    for (int kk = 0; kk < 16; ++kk) {
      const float xv = xs[kk][tid];
#pragma unroll
      for (int j = 0; j < 8; ++j) {
        const int oc = oc0 + j;
        const float wv = (oc < kFeatC) ? wt[oc * kInCh + ic0 + kk] : 0.f;
        acc[j] = fmaf(wv, xv, acc[j]);
      }
    }
    __syncthreads();
  }
#pragma unroll
  for (int j = 0; j < 8; ++j) {
    const int oc = oc0 + j;
    if (oc < kFeatC)
      feat[((size_t)n * kFeatC + oc) * kHW + hw0 + tid] = acc[j] + bias[oc];
  }
}

// ---------------- softmax over depth bins, in place ----------------
__global__ __launch_bounds__(256) void softmax_depth_kernel(float* __restrict__ feat) {
  const int p = blockIdx.x * 256 + threadIdx.x;   // grid exactly covers kNPix
  const int n = p / kHW;
  const int hw = p - n * kHW;
  float* base = feat + (size_t)n * kFeatC * kHW + hw;
  float mx = -3.4e38f;
  for (int d = 0; d < kDB; ++d) mx = fmaxf(mx, base[(size_t)d * kHW]);
  float s = 0.f;
  for (int d = 0; d < kDB; ++d) s += expf(base[(size_t)d * kHW] - mx);
  for (int d = 0; d < kDB; ++d) {
    const float e = expf(base[(size_t)d * kHW] - mx);
    base[(size_t)d * kHW] = e / s;
  }
}

// ---------------- zero the pooled accumulator ----------------
__global__ void zero_kernel(float4* __restrict__ p, int n4) {
  const int i = blockIdx.x * blockDim.x + threadIdx.x;
  if (i < n4) p[i] = make_float4(0.f, 0.f, 0.f, 0.f);
}

// ---------------- lift-splat scatter: pooled[idx][c] += depth*ctx ----------------
__global__ __launch_bounds__(128) void scatter_splat_kernel(
    const float* __restrict__ feat, const double* __restrict__ invm,
    float* __restrict__ pooled) {
  __shared__ float dL[kDB];
  __shared__ int iL[kDB];
  __shared__ float ctxL[kOutC];
  __shared__ int cnt;
  const int tid = threadIdx.x;
  const int pix = blockIdx.x;
  const int n = pix / kHW;
  const int hw = pix - n * kHW;
  const int h = hw / kFW;
  const int w = hw - h * kFW;
  if (tid == 0) cnt = 0;
  __syncthreads();
  if (tid < kDB) {
    const double* A = invm + (size_t)n * 16;        // inv(img_aug)
    const double* L = invm + 96 + (size_t)n * 16;   // inv(lidar2image)
    // frustum values exactly as the reference's fp32 FRUSTUM, widened to fp64
    const double x = (double)(float)((double)w * (703.0 / 87.0));
    const double y = (double)(float)((double)h * (255.0 / 31.0));
    const double d = (double)(1.0f + 0.5f * (float)tid);
    const double p0 = A[0] * x + A[1] * y + A[2]  * d + A[3];
    const double p1 = A[4] * x + A[5] * y + A[6]  * d + A[7];
    const double p2 = A[8] * x + A[9] * y + A[10] * d + A[11];
    const double q0 = p0 * p2, q1 = p1 * p2;
    const double g0 = L[0] * q0 + L[1] * q1 + L[2]  * p2 + L[3];
    const double g1 = L[4] * q0 + L[5] * q1 + L[6]  * p2 + L[7];
    const double g2 = L[8] * q0 + L[9] * q1 + L[10] * p2 + L[11];
    // binning stays in fp64 end-to-end; constants are fp64-of-the-fp32 values
    // (BX - DX/2 evaluated in fp32 as numpy would store it, then widened).
    const double off01 = (double)__fsub_rn(-53.85f, 0.15f);
    const double fx = (g0 - off01) / (double)0.3f;
    const double fy = (g1 - off01) / (double)0.3f;
    const double fz = (g2 - (double)(-10.0f)) / (double)20.0f;
    const int gx = (int)fx;   // C trunc-toward-zero == numpy astype(int32)
    const int gy = (int)fy;
    const int gz = (int)fz;
    if (gx >= 0 && gx < kNX && gy >= 0 && gy < kNX && gz == 0) {
      const float dv = feat[((size_t)n * kFeatC + tid) * kHW + hw];
      const int pos = atomicAdd(&cnt, 1);
      dL[pos] = dv;
      iL[pos] = (gx * kNX + gy) * kOutC;
    }
  }
  if (tid < kOutC)
    ctxL[tid] = feat[((size_t)n * kFeatC + kDB + tid) * kHW + hw];
  __syncthreads();
  const int tot = cnt * kOutC;
  for (int q = tid; q < tot; q += 128) {
    const int e = q / kOutC;
    const int c = q - e * kOutC;
    atomicAdd(pooled + iL[e] + c, dL[e] * ctxL[c]);
  }
}

// ---------------- pooled [vox][c] -> bev [c][vox] ----------------
__global__ __launch_bounds__(256) void pool_transpose_kernel(
    const float* __restrict__ pooled, float* __restrict__ bev) {
  __shared__ float t[32][kOutC + 1];
  const int tid = threadIdx.x;
  const int s0 = blockIdx.x * 32;   // kNVox % 32 == 0
  for (int e = tid; e < 32 * kOutC; e += 256) {
    const int r = e / kOutC;
    const int c = e - r * kOutC;
    t[r][c] = pooled[(size_t)(s0 + r) * kOutC + c];
  }
  __syncthreads();
  for (int e = tid; e < 32 * kOutC; e += 256) {
    const int c = e >> 5;
    const int r = e & 31;
    bev[(size_t)c * kNVox + s0 + r] = t[r][c];
  }
}

// ---------------- 3x3 conv + BN + ReLU (pad=1), templated stride ----------------
template <int S>
__global__ __launch_bounds__(256) void conv3x3_bn_relu_kernel(
    const float* __restrict__ in, const int IHW,
    const float* __restrict__ wgt,
    const float* __restrict__ bng, const float* __restrict__ bnb,
    const float* __restrict__ bnm, const float* __restrict__ bnv,
    float* __restrict__ out, const int OHW) {
  constexpr int TW = 32, TH = 8, OCB = 16;
  constexpr int ITW = (TW - 1) * S + 3;
  constexpr int ITH = (TH - 1) * S + 3;
  constexpr int ICC = (S == 1) ? 8 : 4;
  constexpr int LDW = ITW + ((S == 2) ? 2 : 0);  // pad to kill 4-way bank conflict at S=2
  __shared__ float tile[ICC][ITH][LDW];
  const int tid = threadIdx.x;
  const int tx = tid & 31;
  const int ty = tid >> 5;
  const int ox = blockIdx.x * TW + tx;
  const int oy = blockIdx.y * TH + ty;
  const int oc0 = blockIdx.z * OCB;
  const int bx0 = blockIdx.x * TW * S - 1;
  const int by0 = blockIdx.y * TH * S - 1;
  float acc[OCB];
#pragma unroll
  for (int j = 0; j < OCB; ++j) acc[j] = 0.f;

  for (int ic0 = 0; ic0 < kOutC; ic0 += ICC) {
    constexpr int ELEMS = ICC * ITH * ITW;
    for (int e = tid; e < ELEMS; e += 256) {
      const int ic = e / (ITH * ITW);
      const int rr = e - ic * (ITH * ITW);
      const int r = rr / ITW;
      const int cc = rr - r * ITW;
      const int gy = by0 + r;
      const int gx = bx0 + cc;
      float val = 0.f;
      if ((unsigned)gy < (unsigned)IHW && (unsigned)gx < (unsigned)IHW)
        val = in[((size_t)(ic0 + ic) * IHW + gy) * IHW + gx];
      tile[ic][r][cc] = val;
    }
    __syncthreads();
#pragma unroll
    for (int ic = 0; ic < ICC; ++ic) {
      float xv[9];
#pragma unroll
      for (int dy = 0; dy < 3; ++dy)
#pragma unroll
        for (int dx = 0; dx < 3; ++dx)
          xv[dy * 3 + dx] = tile[ic][ty * S + dy][tx * S + dx];
      const float* wb = wgt + ((size_t)oc0 * kOutC + (ic0 + ic)) * 9;
#pragma unroll
      for (int j = 0; j < OCB; ++j) {
        const float* wj = wb + (size_t)j * kOutC * 9;   // uniform -> scalar loads
#pragma unroll
        for (int t = 0; t < 9; ++t) acc[j] = fmaf(wj[t], xv[t], acc[j]);
      }
    }
    __syncthreads();
  }

  if (ox < OHW && oy < OHW) {
#pragma unroll
    for (int j = 0; j < OCB; ++j) {
      const int oc = oc0 + j;
      const float inv = 1.0f / sqrtf(bnv[oc] + 1e-5f);
      float val = (acc[j] - bnm[oc]) * (bng[oc] * inv) + bnb[oc];
      val = fmaxf(val, 0.f);
      out[((size_t)oc * OHW + oy) * OHW + ox] = val;
    }
  }
}

// ---------------- final H<->W transpose of (80,180,180) ----------------
__global__ void transpose_out_kernel(const float* __restrict__ in,
                                     float* __restrict__ out) {
  __shared__ float t[32][33];
  const int c = blockIdx.z;
  const int i0 = blockIdx.y * 32;
  const int j0 = blockIdx.x * 32;
  const int tx = threadIdx.x;
  const int ty = threadIdx.y;
  const float* ip = in + (size_t)c * 180 * 180;
  float* op = out + (size_t)c * 180 * 180;
  for (int r = ty; r < 32; r += 8) {
    const int i = i0 + r, j = j0 + tx;
    t[r][tx] = (i < 180 && j < 180) ? ip[i * 180 + j] : 0.f;
  }
  __syncthreads();
  for (int r = ty; r < 32; r += 8) {
    const int j = j0 + r, i = i0 + tx;
    if (j < 180 && i < 180) op[j * 180 + i] = t[tx][r];
  }
}

}  // namespace

extern "C" void kernel_launch(void* const* d_in, const int* in_sizes, int n_in,
                              void* d_out, int out_size, void* d_ws, size_t ws_size,
                              hipStream_t stream) {
  const float* image = (const float*)d_in[0];
  const float* l2i   = (const float*)d_in[1];
  const float* aug   = (const float*)d_in[2];
  const float* dnw   = (const float*)d_in[3];
  const float* dnb   = (const float*)d_in[4];
  const float* c1w = (const float*)d_in[5];
  const float* b1g = (const float*)d_in[6];
  const float* b1b = (const float*)d_in[7];
  const float* b1m = (const float*)d_in[8];
  const float* b1v = (const float*)d_in[9];
  const float* c2w = (const float*)d_in[10];
  const float* b2g = (const float*)d_in[11];
  const float* b2b = (const float*)d_in[12];
  const float* b2m = (const float*)d_in[13];
  const float* b2v = (const float*)d_in[14];
  const float* c3w = (const float*)d_in[15];
  const float* b3g = (const float*)d_in[16];
  const float* b3b = (const float*)d_in[17];
  const float* b3m = (const float*)d_in[18];
  const float* b3v = (const float*)d_in[19];
  float* out = (float*)d_out;

  // Workspace layout (~102 MB + 1.5 KB), with lifetime-based reuse:
  //   feat   [0,   13.4M)  -> later y2 (10.4M)
  //   pooled [16M, 57.5M)  -> later y1 (41.5M)
  //   bev    [60M, 101.5M) -> later y3 (10.4M)
  //   invm   [102M, +1.5K)
  char* ws = (char*)d_ws;
  float*  feat   = (float*)(ws);
  float*  pooled = (float*)(ws + ((size_t)16 << 20));
  float*  bev    = (float*)(ws + ((size_t)60 << 20));
  double* invm   = (double*)(ws + ((size_t)102 << 20));
  float* y1 = pooled;  // pooled dead after pool_transpose
  float* y2 = feat;    // feat dead after scatter
  float* y3 = bev;     // bev dead after conv1

  prep_inverses_kernel<<<1, 64, 0, stream>>>(aug, l2i, invm);
  depthnet_gemm_kernel<<<dim3(kNPix / 256, 25), 256, 0, stream>>>(image, dnw, dnb, feat);
  softmax_depth_kernel<<<kNPix / 256, 256, 0, stream>>>(feat);
  {
    const int n4 = kNVox * kOutC / 4;
    zero_kernel<<<(n4 + 255) / 256, 256, 0, stream>>>((float4*)pooled, n4);
  }
  scatter_splat_kernel<<<kNPix, 128, 0, stream>>>(feat, invm, pooled);
  pool_transpose_kernel<<<kNVox / 32, 256, 0, stream>>>(pooled, bev);
  conv3x3_bn_relu_kernel<1><<<dim3(12, 45, 5), 256, 0, stream>>>(
      bev, 360, c1w, b1g, b1b, b1m, b1v, y1, 360);
  conv3x3_bn_relu_kernel<2><<<dim3(6, 23, 5), 256, 0, stream>>>(
      y1, 360, c2w, b2g, b2b, b2m, b2v, y2, 180);
  conv3x3_bn_relu_kernel<1><<<dim3(6, 23, 5), 256, 0, stream>>>(
      y2, 180, c3w, b3g, b3b, b3m, b3v, y3, 180);
  transpose_out_kernel<<<dim3(6, 6, 80), dim3(32, 8), 0, stream>>>(y3, out);
}

// Round 4
// 1697.983 us; speedup vs baseline: 1.0252x; 1.0252x over previous
//
#include <hip/hip_runtime.h>
#include <math.h>

namespace {

constexpr int kNCam  = 6;
constexpr int kInCh  = 256;
constexpr int kOutC  = 80;
constexpr int kDB    = 118;   // depth bins
constexpr int kFH    = 32;
constexpr int kFW    = 88;
constexpr int kHW    = kFH * kFW;       // 2816
constexpr int kNPix  = kNCam * kHW;     // 16896
constexpr int kFeatC = kDB + kOutC;     // 198
constexpr int kNX    = 360;
constexpr int kNVox  = kNX * kNX;       // 129600

// ---------------- 4x4 matrix inverses (fp64 cofactor) ----------------
// Geometry decision path is kept ENTIRELY in fp64 (inverse -> einsum ->
// binning) to match the fp64 numpy reference; passed with absmax 0.0332.
// DO NOT change anything in the geometry/binning path.
__global__ void prep_inverses_kernel(const float* __restrict__ aug,
                                     const float* __restrict__ l2i,
                                     double* __restrict__ invm) {
  const int t = threadIdx.x;
  if (t >= 12) return;
  const float* s = (t < 6) ? (aug + t * 16) : (l2i + (t - 6) * 16);
  double m[16];
#pragma unroll
  for (int i = 0; i < 16; ++i) m[i] = (double)s[i];
  double inv[16];
  inv[0]  =  m[5]*m[10]*m[15] - m[5]*m[11]*m[14] - m[9]*m[6]*m[15] + m[9]*m[7]*m[14] + m[13]*m[6]*m[11] - m[13]*m[7]*m[10];
  inv[4]  = -m[4]*m[10]*m[15] + m[4]*m[11]*m[14] + m[8]*m[6]*m[15] - m[8]*m[7]*m[14] - m[12]*m[6]*m[11] + m[12]*m[7]*m[10];
  inv[8]  =  m[4]*m[9]*m[15]  - m[4]*m[11]*m[13] - m[8]*m[5]*m[15] + m[8]*m[7]*m[13] + m[12]*m[5]*m[11] - m[12]*m[7]*m[9];
  inv[12] = -m[4]*m[9]*m[14]  + m[4]*m[10]*m[13] + m[8]*m[5]*m[14] - m[8]*m[6]*m[13] - m[12]*m[5]*m[10] + m[12]*m[6]*m[9];
  inv[1]  = -m[1]*m[10]*m[15] + m[1]*m[11]*m[14] + m[9]*m[2]*m[15] - m[9]*m[3]*m[14] - m[13]*m[2]*m[11] + m[13]*m[3]*m[10];
  inv[5]  =  m[0]*m[10]*m[15] - m[0]*m[11]*m[14] - m[8]*m[2]*m[15] + m[8]*m[3]*m[14] + m[12]*m[2]*m[11] - m[12]*m[3]*m[10];
  inv[9]  = -m[0]*m[9]*m[15]  + m[0]*m[11]*m[13] + m[8]*m[1]*m[15] - m[8]*m[3]*m[13] - m[12]*m[1]*m[11] + m[12]*m[3]*m[9];
  inv[13] =  m[0]*m[9]*m[14]  - m[0]*m[10]*m[13] - m[8]*m[1]*m[14] + m[8]*m[2]*m[13] + m[12]*m[1]*m[10] - m[12]*m[2]*m[9];
  inv[2]  =  m[1]*m[6]*m[15]  - m[1]*m[7]*m[14]  - m[5]*m[2]*m[15] + m[5]*m[3]*m[14] + m[13]*m[2]*m[7]  - m[13]*m[3]*m[6];
  inv[6]  = -m[0]*m[6]*m[15]  + m[0]*m[7]*m[14]  + m[4]*m[2]*m[15] - m[4]*m[3]*m[14] - m[12]*m[2]*m[7]  + m[12]*m[3]*m[6];
  inv[10] =  m[0]*m[5]*m[15]  - m[0]*m[7]*m[13]  - m[4]*m[1]*m[15] + m[4]*m[3]*m[13] + m[12]*m[1]*m[7]  - m[12]*m[3]*m[5];
  inv[14] = -m[0]*m[5]*m[14]  + m[0]*m[6]*m[13]  + m[4]*m[1]*m[14] - m[4]*m[2]*m[13] - m[12]*m[1]*m[6]  + m[12]*m[2]*m[5];
  inv[3]  = -m[1]*m[6]*m[11]  + m[1]*m[7]*m[10]  + m[5]*m[2]*m[11] - m[5]*m[3]*m[10] - m[9]*m[2]*m[7]   + m[9]*m[3]*m[6];
  inv[7]  =  m[0]*m[6]*m[11]  - m[0]*m[7]*m[10]  - m[4]*m[2]*m[11] + m[4]*m[3]*m[10] + m[8]*m[2]*m[7]   - m[8]*m[3]*m[6];
  inv[11] = -m[0]*m[5]*m[11]  + m[0]*m[7]*m[9]   + m[4]*m[1]*m[11] - m[4]*m[3]*m[9]  - m[8]*m[1]*m[7]   + m[8]*m[3]*m[5];
  inv[15] =  m[0]*m[5]*m[10]  - m[0]*m[6]*m[9]   - m[4]*m[1]*m[10] + m[4]*m[2]*m[9]  + m[8]*m[1]*m[6]   - m[8]*m[2]*m[5];
  const double det = m[0]*inv[0] + m[1]*inv[4] + m[2]*inv[8] + m[3]*inv[12];
  const double id = 1.0 / det;
#pragma unroll
  for (int i = 0; i < 16; ++i) invm[(size_t)t * 16 + i] = inv[i] * id;
}

// ---------------- depthnet 1x1 conv: feat[n][o][hw] ----------------
__global__ __launch_bounds__(256) void depthnet_gemm_kernel(
    const float* __restrict__ img, const float* __restrict__ wt,
    const float* __restrict__ bias, float* __restrict__ feat) {
  __shared__ float xs[16][256];
  const int tid = threadIdx.x;
  const int p0 = blockIdx.x * 256;       // 2816 % 256 == 0: never straddles cams
  const int n = p0 / kHW;
  const int hw0 = p0 - n * kHW;
  const int oc0 = blockIdx.y * 8;
  float acc[8] = {0.f, 0.f, 0.f, 0.f, 0.f, 0.f, 0.f, 0.f};
  const float* xb = img + (size_t)n * kInCh * kHW + hw0;
  for (int ic0 = 0; ic0 < kInCh; ic0 += 16) {
#pragma unroll
    for (int r = 0; r < 16; ++r)
      xs[r][tid] = xb[(size_t)(ic0 + r) * kHW + tid];
    __syncthreads();
#pragma unroll
    for (int kk = 0; kk < 16; ++kk) {
      const float xv = xs[kk][tid];
#pragma unroll
      for (int j = 0; j < 8; ++j) {
        const int oc = oc0 + j;
        const float wv = (oc < kFeatC) ? wt[oc * kInCh + ic0 + kk] : 0.f;
        acc[j] = fmaf(wv, xv, acc[j]);
      }
    }
    __syncthreads();
  }
#pragma unroll
  for (int j = 0; j < 8; ++j) {
    const int oc = oc0 + j;
    if (oc < kFeatC)
      feat[((size_t)n * kFeatC + oc) * kHW + hw0 + tid] = acc[j] + bias[oc];
  }
}

// ---------------- softmax over depth bins, in place ----------------
__global__ __launch_bounds__(256) void softmax_depth_kernel(float* __restrict__ feat) {
  const int p = blockIdx.x * 256 + threadIdx.x;   // grid exactly covers kNPix
  const int n = p / kHW;
  const int hw = p - n * kHW;
  float* base = feat + (size_t)n * kFeatC * kHW + hw;
  float mx = -3.4e38f;
  for (int d = 0; d < kDB; ++d) mx = fmaxf(mx, base[(size_t)d * kHW]);
  float s = 0.f;
  for (int d = 0; d < kDB; ++d) s += expf(base[(size_t)d * kHW] - mx);
  for (int d = 0; d < kDB; ++d) {
    const float e = expf(base[(size_t)d * kHW] - mx);
    base[(size_t)d * kHW] = e / s;
  }
}

// ---------------- zero the pooled accumulator ----------------
__global__ void zero_kernel(float4* __restrict__ p, int n4) {
  const int i = blockIdx.x * blockDim.x + threadIdx.x;
  if (i < n4) p[i] = make_float4(0.f, 0.f, 0.f, 0.f);
}

// ---------------- lift-splat scatter: pooled[idx][c] += depth*ctx ----------------
__global__ __launch_bounds__(128) void scatter_splat_kernel(
    const float* __restrict__ feat, const double* __restrict__ invm,
    float* __restrict__ pooled) {
  __shared__ float dL[kDB];
  __shared__ int iL[kDB];
  __shared__ float ctxL[kOutC];
  __shared__ int cnt;
  const int tid = threadIdx.x;
  const int pix = blockIdx.x;
  const int n = pix / kHW;
  const int hw = pix - n * kHW;
  const int h = hw / kFW;
  const int w = hw - h * kFW;
  if (tid == 0) cnt = 0;
  __syncthreads();
  if (tid < kDB) {
    const double* A = invm + (size_t)n * 16;        // inv(img_aug)
    const double* L = invm + 96 + (size_t)n * 16;   // inv(lidar2image)
    const double x = (double)(float)((double)w * (703.0 / 87.0));
    const double y = (double)(float)((double)h * (255.0 / 31.0));
    const double d = (double)(1.0f + 0.5f * (float)tid);
    const double p0 = A[0] * x + A[1] * y + A[2]  * d + A[3];
    const double p1 = A[4] * x + A[5] * y + A[6]  * d + A[7];
    const double p2 = A[8] * x + A[9] * y + A[10] * d + A[11];
    const double q0 = p0 * p2, q1 = p1 * p2;
    const double g0 = L[0] * q0 + L[1] * q1 + L[2]  * p2 + L[3];
    const double g1 = L[4] * q0 + L[5] * q1 + L[6]  * p2 + L[7];
    const double g2 = L[8] * q0 + L[9] * q1 + L[10] * p2 + L[11];
    const double off01 = (double)__fsub_rn(-53.85f, 0.15f);
    const double fx = (g0 - off01) / (double)0.3f;
    const double fy = (g1 - off01) / (double)0.3f;
    const double fz = (g2 - (double)(-10.0f)) / (double)20.0f;
    const int gx = (int)fx;   // C trunc-toward-zero == numpy astype(int32)
    const int gy = (int)fy;
    const int gz = (int)fz;
    if (gx >= 0 && gx < kNX && gy >= 0 && gy < kNX && gz == 0) {
      const float dv = feat[((size_t)n * kFeatC + tid) * kHW + hw];
      const int pos = atomicAdd(&cnt, 1);
      dL[pos] = dv;
      iL[pos] = (gx * kNX + gy) * kOutC;
    }
  }
  if (tid < kOutC)
    ctxL[tid] = feat[((size_t)n * kFeatC + kDB + tid) * kHW + hw];
  __syncthreads();
  const int tot = cnt * kOutC;
  for (int q = tid; q < tot; q += 128) {
    const int e = q / kOutC;
    const int c = q - e * kOutC;
    atomicAdd(pooled + iL[e] + c, dL[e] * ctxL[c]);
  }
}

// ---------------- pooled [vox][c] -> bev [c][vox] ----------------
__global__ __launch_bounds__(256) void pool_transpose_kernel(
    const float* __restrict__ pooled, float* __restrict__ bev) {
  __shared__ float t[32][kOutC + 1];
  const int tid = threadIdx.x;
  const int s0 = blockIdx.x * 32;   // kNVox % 32 == 0
  for (int e = tid; e < 32 * kOutC; e += 256) {
    const int r = e / kOutC;
    const int c = e - r * kOutC;
    t[r][c] = pooled[(size_t)(s0 + r) * kOutC + c];
  }
  __syncthreads();
  for (int e = tid; e < 32 * kOutC; e += 256) {
    const int c = e >> 5;
    const int r = e & 31;
    bev[(size_t)c * kNVox + s0 + r] = t[r][c];
  }
}

// ---------------- 3x3 conv + BN + ReLU, v2 ----------------
// Latency/fetch fix vs v1: (1) OCB raised (fewer z-replicated input
// re-fetches), (2) double-buffered LDS with register-staged prefetch:
// chunk k+1's global loads issue BEFORE chunk k's FMA phase -> L2/LLC
// latency hides under >=1440 cyc of FMA; one barrier per chunk.
// Numerics: ic ascending, taps (dy,dx) ascending per ic, fmaf chain into
// acc -> identical rounding to the v1 kernel that passed.
template <int S, int TW, int TH, int OCB, int ICC, int MINW>
__global__ __launch_bounds__(256, MINW) void conv3x3_v2_kernel(
    const float* __restrict__ in, const int IHW,
    const float* __restrict__ wgt,
    const float* __restrict__ bng, const float* __restrict__ bnb,
    const float* __restrict__ bnm, const float* __restrict__ bnv,
    float* __restrict__ out, const int OHW) {
  constexpr int ITW = (TW - 1) * S + 3;
  constexpr int ITH = (TH - 1) * S + 3;
  constexpr int ELEMS = ICC * ITH * ITW;
  constexpr int STG = (ELEMS + 255) / 256;
  constexpr int NCH = kOutC / ICC;
  __shared__ float lds[2][ELEMS];
  const int tid = threadIdx.x;
  const int tx = tid % TW;
  const int ty = tid / TW;
  const int ox = blockIdx.x * TW + tx;
  const int oy = blockIdx.y * TH + ty;
  const int oc0 = blockIdx.z * OCB;
  const int bx0 = blockIdx.x * TW * S - 1;
  const int by0 = blockIdx.y * TH * S - 1;

  float acc[OCB];
#pragma unroll
  for (int j = 0; j < OCB; ++j) acc[j] = 0.f;
  float stg[STG];

  // stage chunk (global -> regs), bounds-checked zero padding
  auto load_chunk = [&](int icb) {
#pragma unroll
    for (int s = 0; s < STG; ++s) {
      const int e = tid + s * 256;
      float v = 0.f;
      if (e < ELEMS) {
        const int ic = e / (ITH * ITW);
        const int rr = e - ic * (ITH * ITW);
        const int r = rr / ITW;
        const int cc = rr - r * ITW;
        const int gy = by0 + r;
        const int gx = bx0 + cc;
        if ((unsigned)gy < (unsigned)IHW && (unsigned)gx < (unsigned)IHW)
          v = in[((size_t)(icb + ic) * IHW + gy) * IHW + gx];
      }
      stg[s] = v;
    }
  };
  auto store_chunk = [&](int b) {
#pragma unroll
    for (int s = 0; s < STG; ++s) {
      const int e = tid + s * 256;
      if (e < ELEMS) lds[b][e] = stg[s];
    }
  };

  load_chunk(0);
  store_chunk(0);
  __syncthreads();

  for (int c = 0; c < NCH; ++c) {
    if (c + 1 < NCH) load_chunk((c + 1) * ICC);   // prefetch next chunk
    const float* tb = lds[c & 1];
    const int icb = c * ICC;
    for (int ii = 0; ii < ICC; ++ii) {
      float xv[9];
#pragma unroll
      for (int dy = 0; dy < 3; ++dy)
#pragma unroll
        for (int dx = 0; dx < 3; ++dx)
          xv[dy * 3 + dx] = tb[(ii * ITH + ty * S + dy) * ITW + tx * S + dx];
      const float* wb = wgt + ((size_t)oc0 * kOutC + (icb + ii)) * 9;
#pragma unroll
      for (int j = 0; j < OCB; ++j) {
        const float* wj = wb + (size_t)j * kOutC * 9;   // uniform -> s_loads
#pragma unroll
        for (int t = 0; t < 9; ++t) acc[j] = fmaf(wj[t], xv[t], acc[j]);
      }
    }
    if (c + 1 < NCH) {
      store_chunk((c + 1) & 1);   // other buffer: no race with compute(c)
      __syncthreads();
    }
  }

  if (ox < OHW && oy < OHW) {
#pragma unroll
    for (int j = 0; j < OCB; ++j) {
      const int oc = oc0 + j;
      const float inv = 1.0f / sqrtf(bnv[oc] + 1e-5f);
      float val = (acc[j] - bnm[oc]) * (bng[oc] * inv) + bnb[oc];
      val = fmaxf(val, 0.f);
      out[((size_t)oc * OHW + oy) * OHW + ox] = val;
    }
  }
}

// ---------------- final H<->W transpose of (80,180,180) ----------------
__global__ void transpose_out_kernel(const float* __restrict__ in,
                                     float* __restrict__ out) {
  __shared__ float t[32][33];
  const int c = blockIdx.z;
  const int i0 = blockIdx.y * 32;
  const int j0 = blockIdx.x * 32;
  const int tx = threadIdx.x;
  const int ty = threadIdx.y;
  const float* ip = in + (size_t)c * 180 * 180;
  float* op = out + (size_t)c * 180 * 180;
  for (int r = ty; r < 32; r += 8) {
    const int i = i0 + r, j = j0 + tx;
    t[r][tx] = (i < 180 && j < 180) ? ip[i * 180 + j] : 0.f;
  }
  __syncthreads();
  for (int r = ty; r < 32; r += 8) {
    const int j = j0 + r, i = i0 + tx;
    if (j < 180 && i < 180) op[j * 180 + i] = t[tx][r];
  }
}

}  // namespace

extern "C" void kernel_launch(void* const* d_in, const int* in_sizes, int n_in,
                              void* d_out, int out_size, void* d_ws, size_t ws_size,
                              hipStream_t stream) {
  const float* image = (const float*)d_in[0];
  const float* l2i   = (const float*)d_in[1];
  const float* aug   = (const float*)d_in[2];
  const float* dnw   = (const float*)d_in[3];
  const float* dnb   = (const float*)d_in[4];
  const float* c1w = (const float*)d_in[5];
  const float* b1g = (const float*)d_in[6];
  const float* b1b = (const float*)d_in[7];
  const float* b1m = (const float*)d_in[8];
  const float* b1v = (const float*)d_in[9];
  const float* c2w = (const float*)d_in[10];
  const float* b2g = (const float*)d_in[11];
  const float* b2b = (const float*)d_in[12];
  const float* b2m = (const float*)d_in[13];
  const float* b2v = (const float*)d_in[14];
  const float* c3w = (const float*)d_in[15];
  const float* b3g = (const float*)d_in[16];
  const float* b3b = (const float*)d_in[17];
  const float* b3m = (const float*)d_in[18];
  const float* b3v = (const float*)d_in[19];
  float* out = (float*)d_out;

  // Workspace layout (~102 MB + 1.5 KB), with lifetime-based reuse:
  //   feat   [0,   13.4M)  -> later y2 (10.4M)
  //   pooled [16M, 57.5M)  -> later y1 (41.5M)
  //   bev    [60M, 101.5M) -> later y3 (10.4M)
  //   invm   [102M, +1.5K)
  char* ws = (char*)d_ws;
  float*  feat   = (float*)(ws);
  float*  pooled = (float*)(ws + ((size_t)16 << 20));
  float*  bev    = (float*)(ws + ((size_t)60 << 20));
  double* invm   = (double*)(ws + ((size_t)102 << 20));
  float* y1 = pooled;  // pooled dead after pool_transpose
  float* y2 = feat;    // feat dead after scatter
  float* y3 = bev;     // bev dead after conv1

  prep_inverses_kernel<<<1, 64, 0, stream>>>(aug, l2i, invm);
  depthnet_gemm_kernel<<<dim3(kNPix / 256, 25), 256, 0, stream>>>(image, dnw, dnb, feat);
  softmax_depth_kernel<<<kNPix / 256, 256, 0, stream>>>(feat);
  {
    const int n4 = kNVox * kOutC / 4;
    zero_kernel<<<(n4 + 255) / 256, 256, 0, stream>>>((float4*)pooled, n4);
  }
  scatter_splat_kernel<<<kNPix, 128, 0, stream>>>(feat, invm, pooled);
  pool_transpose_kernel<<<kNVox / 32, 256, 0, stream>>>(pooled, bev);

  // conv1: 360x360, S=1, tile 32x8, OCB=40 (z=2), ICC=16 dbuf (43.5KB LDS)
  conv3x3_v2_kernel<1, 32, 8, 40, 16, 3><<<dim3(12, 45, 2), 256, 0, stream>>>(
      bev, 360, c1w, b1g, b1b, b1m, b1v, y1, 360);
  // conv2: 360->180 stride2, tile 16x16 (in 33x33), OCB=20 (z=4), ICC=4 (34.8KB)
  conv3x3_v2_kernel<2, 16, 16, 20, 4, 4><<<dim3(12, 12, 4), 256, 0, stream>>>(
      y1, 360, c2w, b2g, b2b, b2m, b2v, y2, 180);
  // conv3: 180x180, S=1, tile 16x16 (in 18x18), OCB=20 (z=4), ICC=16 (41.5KB)
  conv3x3_v2_kernel<1, 16, 16, 20, 16, 3><<<dim3(12, 12, 4), 256, 0, stream>>>(
      y2, 180, c3w, b3g, b3b, b3m, b3v, y3, 180);

  transpose_out_kernel<<<dim3(6, 6, 80), dim3(32, 8), 0, stream>>>(y3, out);
}